// Round 2
// baseline (42.934 us; speedup 1.0000x reference)
//
#include <hip/hip_runtime.h>

#define Bdim 64
#define Mdim 50
#define Ndim 10000
#define Edim 128
#define MT 10   // agents per block; Mdim % MT == 0

__device__ __forceinline__ void dot4(float4 w, const float* __restrict__ x, float& acc) {
    acc += w.x * x[0];
    acc += w.y * x[1];
    acc += w.z * x[2];
    acc += w.w * x[3];
}

// One block per (b, m-tile of MT). 128 threads, thread o owns output channel o.
// out[b,m,o] = gterm[b,o] + sum_j h[b,m,j] * W_a[o, 128+j]
//   gterm[b,o] = b_a[o] + sum_j W_a[o,j] * (b_g[j] + W_g[j,:] . graph[b,:])
//   h[b,m,j]   = b_dp+b_dc+b_nc+b_ps + W_dp[j,:] . dp[b,m,:] + feature linears
__global__ __launch_bounds__(128) void k_fused(
    const float* __restrict__ cities, const float* __restrict__ graph,
    const float* __restrict__ astate,
    const float* __restrict__ W_dp, const float* __restrict__ b_dp,
    const float* __restrict__ W_dc, const float* __restrict__ b_dc,
    const float* __restrict__ W_nc, const float* __restrict__ b_nc,
    const float* __restrict__ W_ps, const float* __restrict__ b_ps,
    const float* __restrict__ W_g,  const float* __restrict__ b_g,
    const float* __restrict__ W_a,  const float* __restrict__ b_a,
    float* __restrict__ out)
{
    const int mt = blockIdx.x;      // 0..Mdim/MT-1
    const int b  = blockIdx.y;      // 0..Bdim-1
    const int o  = threadIdx.x;     // 0..127

    __shared__ float gf[Edim];            // graph[b,:]
    __shared__ float gvec[Edim];          // b_g + W_g @ gf
    __shared__ float dp[MT][2 * Edim];    // gathered city rows
    __shared__ float h[MT][Edim];
    __shared__ float feats[MT][11];
    __shared__ int   cidx[MT][2];

    // ---- stage graph row + agent states ----
    gf[o] = graph[b * Edim + o];
    for (int t = o; t < MT * 13; t += 128) {
        const int mm = t / 13, f = t % 13;
        const float v = astate[((b * Mdim) + (mt * MT + mm)) * 13 + f];
        if (f < 2) cidx[mm][f] = min(max((int)v, 0), Ndim - 1);
        else       feats[mm][f - 2] = v;
    }
    __syncthreads();

    // ---- gather city rows (coalesced 512B rows) + gvec = b_g + W_g @ gf ----
    #pragma unroll
    for (int mm = 0; mm < MT; ++mm) {
        dp[mm][o]        = cities[((size_t)b * Ndim + cidx[mm][0]) * Edim + o];
        dp[mm][Edim + o] = cities[((size_t)b * Ndim + cidx[mm][1]) * Edim + o];
    }
    float gacc = b_g[o];
    {
        const float4* wrow = reinterpret_cast<const float4*>(W_g + o * Edim);
        #pragma unroll 8
        for (int c = 0; c < Edim / 4; ++c) dot4(wrow[c], &gf[c * 4], gacc);
    }
    gvec[o] = gacc;
    __syncthreads();

    // ---- gterm[o] = b_a[o] + W_a[o, :128] . gvec ----
    float gterm = b_a[o];
    {
        const float4* warow = reinterpret_cast<const float4*>(W_a + o * 2 * Edim);
        #pragma unroll 8
        for (int c = 0; c < Edim / 4; ++c) dot4(warow[c], &gvec[c * 4], gterm);
    }

    // ---- h[mm][o] = biases + W_dp[o,:] . dp[mm] + feature linears ----
    const float bias = b_dp[o] + b_dc[o] + b_nc[o] + b_ps[o];
    float acc[MT];
    #pragma unroll
    for (int mm = 0; mm < MT; ++mm) acc[mm] = bias;
    {
        const float4* wrow = reinterpret_cast<const float4*>(W_dp + o * 2 * Edim);
        #pragma unroll 8
        for (int c = 0; c < 2 * Edim / 4; ++c) {
            const float4 w = wrow[c];
            #pragma unroll
            for (int mm = 0; mm < MT; ++mm) dot4(w, &dp[mm][c * 4], acc[mm]);
        }
    }
    {
        float wdc[4], wnc[4], wps[3];
        #pragma unroll
        for (int j = 0; j < 4; ++j) wdc[j] = W_dc[o * 4 + j];
        #pragma unroll
        for (int j = 0; j < 4; ++j) wnc[j] = W_nc[o * 4 + j];
        #pragma unroll
        for (int j = 0; j < 3; ++j) wps[j] = W_ps[o * 3 + j];
        #pragma unroll
        for (int mm = 0; mm < MT; ++mm) {
            float a = acc[mm];
            #pragma unroll
            for (int j = 0; j < 4; ++j) a += feats[mm][j] * wdc[j];
            #pragma unroll
            for (int j = 0; j < 4; ++j) a += feats[mm][4 + j] * wnc[j];
            #pragma unroll
            for (int j = 0; j < 3; ++j) a += feats[mm][8 + j] * wps[j];
            acc[mm] = a;
        }
    }
    #pragma unroll
    for (int mm = 0; mm < MT; ++mm) h[mm][o] = acc[mm];
    __syncthreads();

    // ---- out = gterm + W_a[o, 128:] . h[mm] ----
    float acc2[MT];
    #pragma unroll
    for (int mm = 0; mm < MT; ++mm) acc2[mm] = gterm;
    {
        const float4* warow = reinterpret_cast<const float4*>(W_a + o * 2 * Edim + Edim);
        #pragma unroll 8
        for (int c = 0; c < Edim / 4; ++c) {
            const float4 w = warow[c];
            #pragma unroll
            for (int mm = 0; mm < MT; ++mm) dot4(w, &h[mm][c * 4], acc2[mm]);
        }
    }
    #pragma unroll
    for (int mm = 0; mm < MT; ++mm)
        out[((b * Mdim) + (mt * MT + mm)) * Edim + o] = acc2[mm];
}

extern "C" void kernel_launch(void* const* d_in, const int* in_sizes, int n_in,
                              void* d_out, int out_size, void* d_ws, size_t ws_size,
                              hipStream_t stream) {
    const float* cities = (const float*)d_in[0];
    const float* graph  = (const float*)d_in[1];
    const float* astate = (const float*)d_in[2];
    const float* W_dp = (const float*)d_in[3];
    const float* b_dp = (const float*)d_in[4];
    const float* W_dc = (const float*)d_in[5];
    const float* b_dc = (const float*)d_in[6];
    const float* W_nc = (const float*)d_in[7];
    const float* b_nc = (const float*)d_in[8];
    const float* W_ps = (const float*)d_in[9];
    const float* b_ps = (const float*)d_in[10];
    const float* W_g  = (const float*)d_in[11];
    const float* b_g  = (const float*)d_in[12];
    const float* W_a  = (const float*)d_in[13];
    const float* b_a  = (const float*)d_in[14];
    float* out = (float*)d_out;

    hipLaunchKernelGGL(k_fused, dim3(Mdim / MT, Bdim), dim3(Edim), 0, stream,
                       cities, graph, astate,
                       W_dp, b_dp, W_dc, b_dc, W_nc, b_nc, W_ps, b_ps,
                       W_g, b_g, W_a, b_a, out);
}

// Round 3
// 18.691 us; speedup vs baseline: 2.2971x; 2.2971x over previous
//
#include <hip/hip_runtime.h>

#define Bdim 64
#define Mdim 50
#define Ndim 10000
#define Edim 128
#define NROWS (Bdim * Mdim)     // 3200
#define NT 200                  // row tiles of 16 (3200/16)
#define KT1 9                   // GEMM1 K-tiles (288/32)
#define KT2 4                   // GEMM2 K-tiles (128/32)

using s8v   = __attribute__((ext_vector_type(8))) short;
using f32x4 = __attribute__((ext_vector_type(4))) float;

// ws byte offsets
#define XFRAG_OFF   0                            // [NT][KT1][64] s8v  : 1,843,200 B
#define WCFRAG_OFF  1843200                      // [8][KT1][64] s8v   : 73,728 B
#define WA2FRAG_OFF (1843200 + 73728)            // [8][KT2][64] s8v   : 32,768 B
#define GTERM_OFF   (1843200 + 73728 + 32768)    // [64][128] f32      : 32,768 B
#define HBIAS_OFF   (GTERM_OFF + 32768)          // [128] f32

__device__ __forceinline__ short f2bf(float x) {
    union { float f; unsigned u; } v; v.f = x;
    unsigned r = (v.u + 0x7fffu + ((v.u >> 16) & 1u)) >> 16;
    return (short)r;
}

__device__ __forceinline__ void dot4(float4 w, const float* __restrict__ x, float& acc) {
    acc += w.x * x[0]; acc += w.y * x[1]; acc += w.z * x[2]; acc += w.w * x[3];
}

// blocks 0..49: X fragments (wave w -> row-tile 4*bid+w)
// blocks 50..57: Wc fragments (n = bid-50)
// blocks 58..65: Wa2 fragments (n = bid-58)
// blocks 66..129: gterm (b = bid-66), b==0 also writes hbias
__global__ __launch_bounds__(256) void k_prep(
    const float* __restrict__ cities, const float* __restrict__ graph,
    const float* __restrict__ astate,
    const float* __restrict__ W_dp, const float* __restrict__ b_dp,
    const float* __restrict__ W_dc, const float* __restrict__ b_dc,
    const float* __restrict__ W_nc, const float* __restrict__ b_nc,
    const float* __restrict__ W_ps, const float* __restrict__ b_ps,
    const float* __restrict__ W_g,  const float* __restrict__ b_g,
    const float* __restrict__ W_a,  const float* __restrict__ b_a,
    char* __restrict__ ws)
{
    const int bid = blockIdx.x, tid = threadIdx.x;
    const int w = tid >> 6, l = tid & 63;
    const int r16 = l & 15, h = l >> 4;

    __shared__ float gf[Edim];
    __shared__ float gvec[Edim];

    if (bid < 50) {
        // ---- X fragments: tile t, rows 16t..16t+15, K = [city0(128) | city1(128) | feats(11) | 0...] ----
        s8v* Xf = (s8v*)(ws + XFRAG_OFF);
        const int t = bid * 4 + w;
        const int R = t * 16 + r16;
        const int b = R / Mdim;
        const float* as = astate + R * 13;
        int i0 = (int)as[0]; i0 = min(max(i0, 0), Ndim - 1);
        int i1 = (int)as[1]; i1 = min(max(i1, 0), Ndim - 1);
        const float* row0 = cities + ((size_t)b * Ndim + i0) * Edim;
        const float* row1 = cities + ((size_t)b * Ndim + i1) * Edim;
        #pragma unroll
        for (int kt = 0; kt < 8; ++kt) {
            const int c0 = kt * 32 + h * 8;
            const float* src = (c0 < Edim) ? (row0 + c0) : (row1 + (c0 - Edim));
            s8v v;
            #pragma unroll
            for (int j = 0; j < 8; ++j) v[j] = f2bf(src[j]);
            Xf[(t * KT1 + kt) * 64 + l] = v;
        }
        {   // kt = 8: cols 256..287 -> feats 0..10, rest zero
            s8v v = (s8v)0;
            #pragma unroll
            for (int j = 0; j < 8; ++j) {
                const int c = h * 8 + j;
                if (c < 11) v[j] = f2bf(as[2 + c]);
            }
            Xf[(t * KT1 + 8) * 64 + l] = v;
        }
    } else if (bid < 58) {
        // ---- Wc fragments: Wc[o][0:256]=W_dp, [256:260]=W_dc, [260:264]=W_nc, [264:267]=W_ps ----
        s8v* Wf = (s8v*)(ws + WCFRAG_OFF);
        const int n = bid - 50;
        const int o = n * 16 + r16;
        for (int kt = w; kt < KT1; kt += 4) {
            s8v v;
            #pragma unroll
            for (int j = 0; j < 8; ++j) {
                const int c = kt * 32 + h * 8 + j;
                float x = 0.f;
                if (c < 256)      x = W_dp[o * 256 + c];
                else if (c < 260) x = W_dc[o * 4 + (c - 256)];
                else if (c < 264) x = W_nc[o * 4 + (c - 260)];
                else if (c < 267) x = W_ps[o * 3 + (c - 264)];
                v[j] = f2bf(x);
            }
            Wf[(n * KT1 + kt) * 64 + l] = v;
        }
    } else if (bid < 66) {
        // ---- Wa2 fragments: Wa2[o][c] = W_a[o][128+c] ----
        s8v* Wf = (s8v*)(ws + WA2FRAG_OFF);
        const int n = bid - 58;
        const int o = n * 16 + r16;
        const int kt = w;  // 4 waves -> kt 0..3
        s8v v;
        #pragma unroll
        for (int j = 0; j < 8; ++j) {
            const int c = kt * 32 + h * 8 + j;
            v[j] = f2bf(W_a[o * 2 * Edim + Edim + c]);
        }
        Wf[(n * KT2 + kt) * 64 + l] = v;
    } else {
        // ---- gterm[b][o] = b_a[o] + W_a[o,:128] . (b_g + W_g @ graph[b]) ----
        const int b = bid - 66;
        const int o = tid;
        float* gterm = (float*)(ws + GTERM_OFF);
        float* hbias = (float*)(ws + HBIAS_OFF);
        if (o < Edim) gf[o] = graph[b * Edim + o];
        __syncthreads();
        if (o < Edim) {
            float gacc = b_g[o];
            const float4* wrow = (const float4*)(W_g + o * Edim);
            #pragma unroll 8
            for (int c = 0; c < Edim / 4; ++c) dot4(wrow[c], &gf[c * 4], gacc);
            gvec[o] = gacc;
        }
        __syncthreads();
        if (o < Edim) {
            float gt = b_a[o];
            const float4* warow = (const float4*)(W_a + o * 2 * Edim);
            #pragma unroll 8
            for (int c = 0; c < Edim / 4; ++c) dot4(warow[c], &gvec[c * 4], gt);
            gterm[b * Edim + o] = gt;
            if (b == 0) hbias[o] = b_dp[o] + b_dc[o] + b_nc[o] + b_ps[o];
        }
    }
}

// 200 blocks x 256 thr. Block t: rows 16t..16t+15.
// Wave w owns output n-tiles {2w, 2w+1} (cols 32w..32w+31).
__global__ __launch_bounds__(256) void k_main(
    const char* __restrict__ ws, float* __restrict__ out)
{
    const int t = blockIdx.x;
    const int w = threadIdx.x >> 6, l = threadIdx.x & 63;
    const int r16 = l & 15, h = l >> 4;
    const int n0 = 2 * w, n1 = 2 * w + 1;

    const s8v* Xf   = (const s8v*)(ws + XFRAG_OFF);
    const s8v* Wcf  = (const s8v*)(ws + WCFRAG_OFF);
    const s8v* Wa2f = (const s8v*)(ws + WA2FRAG_OFF);
    const float* gterm = (const float*)(ws + GTERM_OFF);
    const float* hbias = (const float*)(ws + HBIAS_OFF);

    __shared__ __align__(16) short hlds[16 * 136];  // h tile, stride 136 (2-way max on b128 reads)

    // ---- GEMM1: h[16][128] = X_tile @ Wc^T ----
    f32x4 acc0 = {0.f, 0.f, 0.f, 0.f}, acc1 = acc0;
    #pragma unroll
    for (int kt = 0; kt < KT1; ++kt) {
        const s8v a  = Xf[(t * KT1 + kt) * 64 + l];
        const s8v b0 = Wcf[(n0 * KT1 + kt) * 64 + l];
        const s8v b1 = Wcf[(n1 * KT1 + kt) * 64 + l];
        acc0 = __builtin_amdgcn_mfma_f32_16x16x32_bf16(a, b0, acc0, 0, 0, 0);
        acc1 = __builtin_amdgcn_mfma_f32_16x16x32_bf16(a, b1, acc1, 0, 0, 0);
    }
    // h += hbias, convert bf16, stash in LDS (C/D: col=lane&15, row=(lane>>4)*4+reg)
    const float hb0 = hbias[n0 * 16 + r16];
    const float hb1 = hbias[n1 * 16 + r16];
    #pragma unroll
    for (int r = 0; r < 4; ++r) {
        const int row = h * 4 + r;
        hlds[row * 136 + n0 * 16 + r16] = f2bf(acc0[r] + hb0);
        hlds[row * 136 + n1 * 16 + r16] = f2bf(acc1[r] + hb1);
    }
    __syncthreads();

    // ---- GEMM2: out_tile = h @ Wa2^T + gterm ----
    f32x4 a20 = {0.f, 0.f, 0.f, 0.f}, a21 = a20;
    #pragma unroll
    for (int kt = 0; kt < KT2; ++kt) {
        const s8v ha = *(const s8v*)&hlds[r16 * 136 + kt * 32 + h * 8];
        const s8v b0 = Wa2f[(n0 * KT2 + kt) * 64 + l];
        const s8v b1 = Wa2f[(n1 * KT2 + kt) * 64 + l];
        a20 = __builtin_amdgcn_mfma_f32_16x16x32_bf16(ha, b0, a20, 0, 0, 0);
        a21 = __builtin_amdgcn_mfma_f32_16x16x32_bf16(ha, b1, a21, 0, 0, 0);
    }
    #pragma unroll
    for (int r = 0; r < 4; ++r) {
        const int row = h * 4 + r;
        const int R = t * 16 + row;
        const int bb = R / Mdim;
        out[R * Edim + n0 * 16 + r16] = a20[r] + gterm[bb * Edim + n0 * 16 + r16];
        out[R * Edim + n1 * 16 + r16] = a21[r] + gterm[bb * Edim + n1 * 16 + r16];
    }
}

extern "C" void kernel_launch(void* const* d_in, const int* in_sizes, int n_in,
                              void* d_out, int out_size, void* d_ws, size_t ws_size,
                              hipStream_t stream) {
    const float* cities = (const float*)d_in[0];
    const float* graph  = (const float*)d_in[1];
    const float* astate = (const float*)d_in[2];
    const float* W_dp = (const float*)d_in[3];
    const float* b_dp = (const float*)d_in[4];
    const float* W_dc = (const float*)d_in[5];
    const float* b_dc = (const float*)d_in[6];
    const float* W_nc = (const float*)d_in[7];
    const float* b_nc = (const float*)d_in[8];
    const float* W_ps = (const float*)d_in[9];
    const float* b_ps = (const float*)d_in[10];
    const float* W_g  = (const float*)d_in[11];
    const float* b_g  = (const float*)d_in[12];
    const float* W_a  = (const float*)d_in[13];
    const float* b_a  = (const float*)d_in[14];
    char* ws = (char*)d_ws;
    float* out = (float*)d_out;

    hipLaunchKernelGGL(k_prep, dim3(130), dim3(256), 0, stream,
                       cities, graph, astate,
                       W_dp, b_dp, W_dc, b_dc, W_nc, b_nc, W_ps, b_ps,
                       W_g, b_g, W_a, b_a, ws);
    hipLaunchKernelGGL(k_main, dim3(NT), dim3(256), 0, stream, ws, out);
}

// Round 5
// 18.348 us; speedup vs baseline: 2.3400x; 1.0187x over previous
//
#include <hip/hip_runtime.h>

#define Bdim 64
#define Mdim 50
#define Ndim 10000
#define Edim 128
#define NT 200                  // row tiles of 16 (3200/16)
#define KT1 9                   // GEMM1 K-tiles (288/32); col 267 = bias (X col 267 = 1.0)
#define KT2 4                   // GEMM2 K-tiles (128/32)
#define XSTR 296                // LDS X stride in shorts: 16B-aligned frags, 2-way bank max

using s8v   = __attribute__((ext_vector_type(8))) short;
using f32x4 = __attribute__((ext_vector_type(4))) float;

// ws byte offsets
#define WCFRAG_OFF  0                    // [8][KT1][64] s8v : 73,728 B
#define WA2FRAG_OFF 73728                // [8][KT2][64] s8v : 32,768 B
#define GTERM_OFF   (73728 + 32768)      // [64][128] f32    : 32,768 B

__device__ __forceinline__ short f2bf(float x) {
    union { float f; unsigned u; } v; v.f = x;
    unsigned r = (v.u + 0x7fffu + ((v.u >> 16) & 1u)) >> 16;
    return (short)r;
}

__device__ __forceinline__ void dot4(float4 w, const float* __restrict__ x, float& acc) {
    acc += w.x * x[0]; acc += w.y * x[1]; acc += w.z * x[2]; acc += w.w * x[3];
}

// blocks 0..7: Wc fragments (n = bid), bias folded in as col 267
// blocks 8..15: Wa2 fragments (n = bid-8)
// blocks 16..79: gterm (b = bid-16), 2 threads per output channel
__global__ __launch_bounds__(256) void k_prep(
    const float* __restrict__ graph,
    const float* __restrict__ W_dp, const float* __restrict__ b_dp,
    const float* __restrict__ W_dc, const float* __restrict__ b_dc,
    const float* __restrict__ W_nc, const float* __restrict__ b_nc,
    const float* __restrict__ W_ps, const float* __restrict__ b_ps,
    const float* __restrict__ W_g,  const float* __restrict__ b_g,
    const float* __restrict__ W_a,  const float* __restrict__ b_a,
    char* __restrict__ ws)
{
    const int bid = blockIdx.x, tid = threadIdx.x;
    const int w = tid >> 6, l = tid & 63;
    const int r16 = l & 15, h = l >> 4;

    __shared__ float gf[Edim];
    __shared__ float gvec[Edim];
    __shared__ float part[2][Edim];

    if (bid < 8) {
        s8v* Wf = (s8v*)(ws + WCFRAG_OFF);
        const int n = bid, o = n * 16 + r16;
        for (int kt = w; kt < KT1; kt += 4) {
            s8v v;
            #pragma unroll
            for (int j = 0; j < 8; ++j) {
                const int c = kt * 32 + h * 8 + j;
                float x = 0.f;
                if (c < 256)       x = W_dp[o * 256 + c];
                else if (c < 260)  x = W_dc[o * 4 + (c - 256)];
                else if (c < 264)  x = W_nc[o * 4 + (c - 260)];
                else if (c < 267)  x = W_ps[o * 3 + (c - 264)];
                else if (c == 267) x = b_dp[o] + b_dc[o] + b_nc[o] + b_ps[o];
                v[j] = f2bf(x);
            }
            Wf[(n * KT1 + kt) * 64 + l] = v;
        }
    } else if (bid < 16) {
        s8v* Wf = (s8v*)(ws + WA2FRAG_OFF);
        const int n = bid - 8, o = n * 16 + r16;
        const int kt = w;
        s8v v;
        #pragma unroll
        for (int j = 0; j < 8; ++j) {
            const int c = kt * 32 + h * 8 + j;
            v[j] = f2bf(W_a[o * 2 * Edim + Edim + c]);
        }
        Wf[(n * KT2 + kt) * 64 + l] = v;
    } else {
        // gterm[b][o] = b_a[o] + W_a[o,:128] . (b_g + W_g @ graph[b])
        const int b = bid - 16;
        const int o = tid & 127, half = tid >> 7;
        float* gterm = (float*)(ws + GTERM_OFF);
        if (tid < Edim) gf[tid] = graph[b * Edim + tid];
        __syncthreads();
        {
            float p = 0.f;
            const float4* wrow = (const float4*)(W_g + o * Edim + half * 64);
            #pragma unroll
            for (int c = 0; c < 16; ++c) dot4(wrow[c], &gf[half * 64 + c * 4], p);
            part[half][o] = p;
        }
        __syncthreads();
        if (tid < Edim) gvec[tid] = b_g[tid] + part[0][tid] + part[1][tid];
        __syncthreads();
        {
            float q = 0.f;
            const float4* warow = (const float4*)(W_a + o * 2 * Edim + half * 64);
            #pragma unroll
            for (int c = 0; c < 16; ++c) dot4(warow[c], &gvec[half * 64 + c * 4], q);
            part[half][o] = q;
        }
        __syncthreads();
        if (tid < Edim) gterm[b * Edim + tid] = b_a[tid] + part[0][tid] + part[1][tid];
    }
}

// 200 blocks x 256 thr. Block t: rows 16t..16t+15. Wave w owns n-tiles {2w, 2w+1}.
__global__ __launch_bounds__(256) void k_main(
    const float* __restrict__ cities, const float* __restrict__ astate,
    const char* __restrict__ ws, float* __restrict__ out)
{
    const int t = blockIdx.x, tid = threadIdx.x;
    const int w = tid >> 6, l = tid & 63;
    const int r16 = l & 15, h = l >> 4;
    const int n0 = 2 * w, n1 = 2 * w + 1;

    const s8v* Wcf  = (const s8v*)(ws + WCFRAG_OFF);
    const s8v* Wa2f = (const s8v*)(ws + WA2FRAG_OFF);
    const float* gterm = (const float*)(ws + GTERM_OFF);

    __shared__ float asrow[16][13];
    __shared__ __align__(16) short Xl[16][XSTR];       // [row][K: city0|city1|feats,1,0pad]
    __shared__ __align__(16) short hlds[16 * 136];

    // ---- stage the 16 agent rows: 208 consecutive floats ----
    if (tid < 16 * 13) asrow[tid / 13][tid % 13] = astate[t * 16 * 13 + tid];
    __syncthreads();

    // ---- gather 32 city rows coalesced (512B segments), convert bf16 into Xl ----
    #pragma unroll
    for (int i = 0; i < 4; ++i) {
        const int f = (i * 256 + tid) * 4;     // 0..4092, step 4
        const int r = f >> 8;                  // row 0..15
        const int c = f & 255;                 // col 0..255 within city0|city1
        const int b = (t * 16 + r) / Mdim;
        int ci = (int)asrow[r][c < 128 ? 0 : 1];
        ci = min(max(ci, 0), Ndim - 1);
        const float4 v = *(const float4*)(cities + ((size_t)b * Ndim + ci) * Edim + (c & 127));
        Xl[r][c]     = f2bf(v.x);
        Xl[r][c + 1] = f2bf(v.y);
        Xl[r][c + 2] = f2bf(v.z);
        Xl[r][c + 3] = f2bf(v.w);
    }
    // feats cols 256..287: 11 feats, col 267 (cc==11) = 1.0 (bias), rest 0.
    // 256 threads x 2 cols each = all 16 rows x 32 cols covered.
    {
        const int r = tid >> 4;            // 0..15
        const int cc0 = (tid & 15) * 2;    // 0,2,...,30
        #pragma unroll
        for (int d = 0; d < 2; ++d) {
            const int cc = cc0 + d;
            float x = 0.f;
            if (cc < 11)       x = asrow[r][2 + cc];
            else if (cc == 11) x = 1.0f;
            Xl[r][256 + cc] = f2bf(x);
        }
    }
    __syncthreads();

    // ---- GEMM1: h[16][128] = X_tile @ Wc^T (bias folded) ----
    f32x4 acc0 = {0.f, 0.f, 0.f, 0.f}, acc1 = acc0;
    #pragma unroll
    for (int kt = 0; kt < KT1; ++kt) {
        const s8v a  = *(const s8v*)&Xl[r16][kt * 32 + h * 8];
        const s8v b0 = Wcf[(n0 * KT1 + kt) * 64 + l];
        const s8v b1 = Wcf[(n1 * KT1 + kt) * 64 + l];
        acc0 = __builtin_amdgcn_mfma_f32_16x16x32_bf16(a, b0, acc0, 0, 0, 0);
        acc1 = __builtin_amdgcn_mfma_f32_16x16x32_bf16(a, b1, acc1, 0, 0, 0);
    }
    // C/D layout: col = lane&15, row = (lane>>4)*4 + reg
    #pragma unroll
    for (int r = 0; r < 4; ++r) {
        const int row = h * 4 + r;
        hlds[row * 136 + n0 * 16 + r16] = f2bf(acc0[r]);
        hlds[row * 136 + n1 * 16 + r16] = f2bf(acc1[r]);
    }
    __syncthreads();

    // ---- GEMM2: out_tile = h @ Wa2^T + gterm ----
    f32x4 a20 = {0.f, 0.f, 0.f, 0.f}, a21 = a20;
    #pragma unroll
    for (int kt = 0; kt < KT2; ++kt) {
        const s8v ha = *(const s8v*)&hlds[r16 * 136 + kt * 32 + h * 8];
        const s8v b0 = Wa2f[(n0 * KT2 + kt) * 64 + l];
        const s8v b1 = Wa2f[(n1 * KT2 + kt) * 64 + l];
        a20 = __builtin_amdgcn_mfma_f32_16x16x32_bf16(ha, b0, a20, 0, 0, 0);
        a21 = __builtin_amdgcn_mfma_f32_16x16x32_bf16(ha, b1, a21, 0, 0, 0);
    }
    #pragma unroll
    for (int r = 0; r < 4; ++r) {
        const int row = h * 4 + r;
        const int R = t * 16 + row;
        const int bb = R / Mdim;
        out[R * Edim + n0 * 16 + r16] = a20[r] + gterm[bb * Edim + n0 * 16 + r16];
        out[R * Edim + n1 * 16 + r16] = a21[r] + gterm[bb * Edim + n1 * 16 + r16];
    }
}

extern "C" void kernel_launch(void* const* d_in, const int* in_sizes, int n_in,
                              void* d_out, int out_size, void* d_ws, size_t ws_size,
                              hipStream_t stream) {
    const float* cities = (const float*)d_in[0];
    const float* graph  = (const float*)d_in[1];
    const float* astate = (const float*)d_in[2];
    const float* W_dp = (const float*)d_in[3];
    const float* b_dp = (const float*)d_in[4];
    const float* W_dc = (const float*)d_in[5];
    const float* b_dc = (const float*)d_in[6];
    const float* W_nc = (const float*)d_in[7];
    const float* b_nc = (const float*)d_in[8];
    const float* W_ps = (const float*)d_in[9];
    const float* b_ps = (const float*)d_in[10];
    const float* W_g  = (const float*)d_in[11];
    const float* b_g  = (const float*)d_in[12];
    const float* W_a  = (const float*)d_in[13];
    const float* b_a  = (const float*)d_in[14];
    char* ws = (char*)d_ws;
    float* out = (float*)d_out;

    hipLaunchKernelGGL(k_prep, dim3(80), dim3(256), 0, stream,
                       graph,
                       W_dp, b_dp, W_dc, b_dc, W_nc, b_nc, W_ps, b_ps,
                       W_g, b_g, W_a, b_a, ws);
    hipLaunchKernelGGL(k_main, dim3(NT), dim3(256), 0, stream,
                       cities, astate, ws, out);
}